// Round 3
// baseline (443.370 us; speedup 1.0000x reference)
//
#include <hip/hip_runtime.h>
#include <stdint.h>

#define N_NODES 100000
#define N_FEAT 128
#define N_EDGES 3200000
#define NCHUNK 8            // 8 chunks x 16 features
#define NODE_BLOCKS 25000   // 4 nodes (waves) per block

// ---------- bf16 helpers ----------
static __device__ __forceinline__ unsigned short f2bf(float f) {
    unsigned int u = __float_as_uint(f);
    u += 0x7FFFu + ((u >> 16) & 1u);   // RNE
    return (unsigned short)(u >> 16);
}

typedef __bf16 bf16x8 __attribute__((ext_vector_type(8)));
typedef float f32x4 __attribute__((ext_vector_type(4)));

// ---------- Kernel 1: x fp32 -> bf16, CHUNKED layout xc[chunk][node][16] ----------
__global__ void k_convert_x(const float* __restrict__ x, unsigned int* __restrict__ xc) {
    long long i = (long long)(blockIdx.x * blockDim.x + threadIdx.x) * 4;
    if (i >= (long long)N_NODES * N_FEAT) return;
    float4 v = *(const float4*)(x + i);
    int node = (int)(i >> 7), f0 = (int)(i & 127);
    int chunk = f0 >> 4, pr = (f0 & 15) >> 1;          // pair index within chunk
    uint2 o;
    o.x = ((unsigned int)f2bf(v.y) << 16) | f2bf(v.x);
    o.y = ((unsigned int)f2bf(v.w) << 16) | f2bf(v.z);
    *(uint2*)(xc + (size_t)chunk * (N_NODES * 8) + (size_t)node * 8 + pr) = o;
}

// ---------- Kernel 1b: filters [K][N] fp32 -> F^T bf16 [N][K] ----------
__global__ void k_convert_f(const float* __restrict__ f, unsigned short* __restrict__ fT) {
    int i = blockIdx.x * blockDim.x + threadIdx.x;   // i = k*128 + n
    if (i >= N_FEAT * N_FEAT) return;
    int k = i >> 7, n = i & 127;
    fT[n * N_FEAT + k] = f2bf(f[i]);
}

// ---------- Kernel 2: CSR row pointers, edge-parallel scatter ----------
__global__ void k_rowptr(const int* __restrict__ dst, int* __restrict__ row_ptr) {
    int e = blockIdx.x * blockDim.x + threadIdx.x;
    if (e >= N_EDGES) return;
    int dcur = dst[e];
    if (e == 0) {
        for (int d = 0; d <= dcur; ++d) row_ptr[d] = 0;
    } else {
        int dprev = dst[e - 1];
        for (int d = dprev + 1; d <= dcur; ++d) row_ptr[d] = e;
    }
    if (e == N_EDGES - 1) {
        for (int d = dcur + 1; d <= N_NODES; ++d) row_ptr[d] = N_EDGES;
    }
}

// ---------- Kernel 2b: pack (src:17b | w:15b fixed-point) into one uint ----------
__global__ void k_meta(const int* __restrict__ src, const float* __restrict__ w,
                       unsigned int* __restrict__ meta) {
    int e = blockIdx.x * blockDim.x + threadIdx.x;
    if (e >= N_EDGES) return;
    unsigned int w15 = (unsigned int)rintf(w[e] * 32767.f);   // w in [0,1) -> <=32767
    meta[e] = ((unsigned int)src[e] << 15) | w15;
}

// ---------- Kernel 3: chunked aggregation ----------
// blockIdx = chunk*NODE_BLOCKS + nodeblock (chunk slow -> L2 temporal locality).
// Wave per node; lane = (edge_sub:3)(feat_pair:3); 32 edges per iteration, 4
// gathers in flight. Chunk table (3.2MB) stays L2-resident; meta loads are nt.
__global__ __launch_bounds__(256) void k_aggregate(
        const unsigned int* __restrict__ xc,     // [8][N][8] uints (bf16x2)
        const unsigned int* __restrict__ meta,   // [E] packed
        const int* __restrict__ row_ptr,
        unsigned int* __restrict__ aggb) {       // [N][64] uints (bf16x2)
    int wave = threadIdx.x >> 6, lane = threadIdx.x & 63;
    int chunk = blockIdx.x / NODE_BLOCKS;
    int node = (blockIdx.x % NODE_BLOCKS) * 4 + wave;
    int esub = lane >> 3, fp = lane & 7;
    const unsigned int* xcc = xc + (size_t)chunk * (N_NODES * 8);
    int start = row_ptr[node], end = row_ptr[node + 1];
    float a0 = 0.f, a1 = 0.f;

    for (int e0 = start; e0 < end; e0 += 32) {
        unsigned int p[4], v[4];
#pragma unroll
        for (int g = 0; g < 4; ++g) {
            int e = e0 + g * 8 + esub;
            p[g] = (e < end) ? __builtin_nontemporal_load(meta + e) : 0u;
        }
#pragma unroll
        for (int g = 0; g < 4; ++g)
            v[g] = xcc[(p[g] >> 15) * 8 + fp];           // 32B/edge, L2-resident
#pragma unroll
        for (int g = 0; g < 4; ++g) {
            float wf = (float)(p[g] & 0x7FFFu);          // fixed-point weight
            a0 = fmaf(wf, __uint_as_float(v[g] << 16), a0);
            a1 = fmaf(wf, __uint_as_float(v[g] & 0xFFFF0000u), a1);
        }
    }
    // reduce across the 8 edge-slots
    for (int d = 8; d < 64; d <<= 1) {
        a0 += __shfl_xor(a0, d);
        a1 += __shfl_xor(a1, d);
    }
    if (esub == 0) {
        const float sc = 1.f / 32767.f;
        unsigned int o = ((unsigned int)f2bf(a1 * sc) << 16) | f2bf(a0 * sc);
        __builtin_nontemporal_store(o, aggb + (size_t)node * 64 + chunk * 8 + fp);
    }
}

// ---------- Kernel 4: out = agg_bf16 @ F  (MFMA bf16, single K pass) ----------
#define LDA 136   // 128 + 8 bf16 pad

__global__ __launch_bounds__(256, 2) void k_gemm(
        const unsigned short* __restrict__ A,   // [M][128] bf16 (agg)
        const unsigned short* __restrict__ BT,  // [128][128] bf16, n-major (F^T)
        float* __restrict__ C) {                // [M][128] fp32
    __shared__ unsigned short Abuf[128 * LDA];
    __shared__ unsigned short Bbuf[128 * LDA];
    int t = threadIdx.x;
    int tileM = blockIdx.x * 128;

    for (int i = 0; i < 8; ++i) {
        int c = t + i * 256;
        int r = c >> 4, c8 = c & 15;
        int grow = tileM + r;
        if (grow >= N_NODES) grow = N_NODES - 1;        // clamp; tail rows unused
        uint4 va = *(const uint4*)(A + (long long)grow * 128 + c8 * 8);
        *(uint4*)(Abuf + r * LDA + c8 * 8) = va;
        uint4 vb = *(const uint4*)(BT + r * 128 + c8 * 8);
        *(uint4*)(Bbuf + r * LDA + c8 * 8) = vb;
    }
    __syncthreads();

    int wave = t >> 6, lane = t & 63;
    int wm = (wave >> 1) * 64, wn = (wave & 1) * 64;    // 64x64 per wave
    int m15 = lane & 15, q = lane >> 4;

    f32x4 acc[4][4];
    for (int i = 0; i < 4; ++i)
        for (int j = 0; j < 4; ++j)
            acc[i][j] = f32x4{0.f, 0.f, 0.f, 0.f};

    for (int kk = 0; kk < 128; kk += 32) {
        bf16x8 a[4], b[4];
        for (int i = 0; i < 4; ++i)
            a[i] = *(const bf16x8*)(Abuf + (wm + i * 16 + m15) * LDA + kk + q * 8);
        for (int j = 0; j < 4; ++j)
            b[j] = *(const bf16x8*)(Bbuf + (wn + j * 16 + m15) * LDA + kk + q * 8);
        for (int i = 0; i < 4; ++i)
            for (int j = 0; j < 4; ++j)
                acc[i][j] = __builtin_amdgcn_mfma_f32_16x16x32_bf16(a[i], b[j], acc[i][j], 0, 0, 0);
    }

    // D row = q*4 + reg, col = lane&15 (m89/m91 layout)
    for (int i = 0; i < 4; ++i) {
        int rowbase = tileM + wm + i * 16 + q * 4;
        for (int j = 0; j < 4; ++j) {
            int col = wn + j * 16 + m15;
            for (int r = 0; r < 4; ++r) {
                int grow = rowbase + r;
                if (grow < N_NODES)
                    C[(long long)grow * 128 + col] = acc[i][j][r];
            }
        }
    }
}

extern "C" void kernel_launch(void* const* d_in, const int* in_sizes, int n_in,
                              void* d_out, int out_size, void* d_ws, size_t ws_size,
                              hipStream_t stream) {
    const float* x        = (const float*)d_in[0];
    const float* filters  = (const float*)d_in[1];
    const int*   edge_src = (const int*)d_in[2];
    const int*   edge_dst = (const int*)d_in[3];
    const float* edge_w   = (const float*)d_in[4];
    float* out = (float*)d_out;

    char* ws = (char*)d_ws;
    unsigned int*   xc   = (unsigned int*)(ws);                            // 25.6 MB
    unsigned int*   aggb = (unsigned int*)(ws + 26ll * 1024 * 1024);       // 25.6 MB
    unsigned short* fT   = (unsigned short*)(ws + 52ll * 1024 * 1024);     // 32 KB
    // scratch that dies before k_gemm writes d_out: meta + row_ptr live in d_out
    unsigned int*   meta = (unsigned int*)d_out;                           // 12.8 MB
    int*            rp   = (int*)((char*)d_out + 13ll * 1024 * 1024);      // 400 KB

    hipLaunchKernelGGL(k_convert_x, dim3(12500), dim3(256), 0, stream, x, xc);
    hipLaunchKernelGGL(k_convert_f, dim3(64),    dim3(256), 0, stream, filters, fT);
    hipLaunchKernelGGL(k_rowptr,    dim3(12500), dim3(256), 0, stream, edge_dst, rp);
    hipLaunchKernelGGL(k_meta,      dim3(12500), dim3(256), 0, stream, edge_src, edge_w, meta);
    hipLaunchKernelGGL(k_aggregate, dim3(NCHUNK * NODE_BLOCKS), dim3(256), 0, stream,
                       xc, meta, rp, aggb);
    hipLaunchKernelGGL(k_gemm,      dim3(782),   dim3(256), 0, stream,
                       (const unsigned short*)aggb, fT, out);
}

// Round 5
// 210.365 us; speedup vs baseline: 2.1076x; 2.1076x over previous
//
#include <hip/hip_runtime.h>
#include <stdint.h>

#define N_NODES 100000
#define N_FEAT 128
#define N_EDGES 3200000

// ---------- bf16 helpers ----------
static __device__ __forceinline__ unsigned int f2bf_u(float f) {
    unsigned int u = __float_as_uint(f);
    u += 0x7FFFu + ((u >> 16) & 1u);   // RNE
    return u >> 16;
}

typedef __bf16 bf16x8 __attribute__((ext_vector_type(8)));
typedef float f32x4 __attribute__((ext_vector_type(4)));

// ---------- Kernel 1 (fused prep): ----------
// blocks [0,25000):      x fp32 -> int8 row-quantized (scale = rowabsmax/127)
// blocks [25000,37500):  CSR row_ptr scatter from sorted edge_dst
// blocks [37500,37564):  filters -> F^T bf16
__global__ __launch_bounds__(256) void k_prep(
        const float* __restrict__ x, unsigned short* __restrict__ xi8,
        float* __restrict__ xscale,
        const float* __restrict__ f, unsigned short* __restrict__ fT,
        const int* __restrict__ dst, int* __restrict__ row_ptr) {
    int b = blockIdx.x;
    if (b < 25000) {
        int wave = threadIdx.x >> 6, lane = threadIdx.x & 63;
        int node = b * 4 + wave;
        float2 v = *(const float2*)(x + (size_t)node * 128 + lane * 2);
        float am = fmaxf(fabsf(v.x), fabsf(v.y));
        for (int d = 1; d < 64; d <<= 1) am = fmaxf(am, __shfl_xor(am, d));
        float s = am * (1.f / 127.f);
        float inv = 127.f / fmaxf(am, 1e-20f);
        int q0 = (int)rintf(v.x * inv), q1 = (int)rintf(v.y * inv);
        xi8[(size_t)node * 64 + lane] =
            (unsigned short)((q0 & 0xFF) | ((q1 & 0xFF) << 8));
        if (lane == 0) xscale[node] = s;
    } else if (b < 37500) {
        int e = (b - 25000) * 256 + threadIdx.x;
        if (e >= N_EDGES) return;
        int dcur = dst[e];
        if (e == 0) {
            for (int d = 0; d <= dcur; ++d) row_ptr[d] = 0;
        } else {
            int dprev = dst[e - 1];
            for (int d = dprev + 1; d <= dcur; ++d) row_ptr[d] = e;
        }
        if (e == N_EDGES - 1) {
            for (int d = dcur + 1; d <= N_NODES; ++d) row_ptr[d] = N_EDGES;
        }
    } else {
        int i = (b - 37500) * 256 + threadIdx.x;   // i = k*128 + n
        if (i >= N_FEAT * N_FEAT) return;
        int k = i >> 7, n = i & 127;
        fT[n * N_FEAT + k] = (unsigned short)f2bf_u(f[i]);
    }
}

// ---------- Kernel 2: per-node weighted aggregation of int8 x ----------
// One wave per node; lane = (half:1)(feat:5). Each step: 2 edges, lane loads
// one uint (4 int8 feats). 8 steps unrolled -> 8 gathers (16 edges) in flight.
// Per-edge scale xscale[src] folded into w during metadata staging (L2-resident
// 400KB table). Pad slots: src=0, w'=0. fp32 accumulate, bf16 out.
__global__ __launch_bounds__(256) void k_aggregate(
        const unsigned int* __restrict__ xi8,    // [N][32] uints (4 int8 each)
        const float* __restrict__ xscale,        // [N]
        const int* __restrict__ src,
        const float* __restrict__ w,
        const int* __restrict__ row_ptr,
        unsigned int* __restrict__ aggb) {       // [N][64] uints (bf16x2)
    __shared__ uint2 smeta[4][64];
    int wave = threadIdx.x >> 6, lane = threadIdx.x & 63;
    int node = blockIdx.x * 4 + wave;
    if (node >= N_NODES) return;
    int half = lane >> 5, f = lane & 31;
    int start = row_ptr[node], end = row_ptr[node + 1];
    float a0 = 0.f, a1 = 0.f, a2 = 0.f, a3 = 0.f;

    for (int e0 = start; e0 < end; e0 += 64) {
        int e = e0 + lane;
        uint2 m = make_uint2(0u, 0u);                    // pad: src=0, w'=0
        if (e < end) {
            int sv = src[e];
            m.x = (unsigned int)sv;
            m.y = __float_as_uint(w[e] * xscale[sv]);    // fold row scale
        }
        smeta[wave][lane] = m;                           // wave-private; no barrier
        int cnt16 = (min(64, end - e0) + 15) & ~15;
        for (int j = 0; j < cnt16; j += 16) {
            unsigned int vv[8]; float wj[8];
#pragma unroll
            for (int u = 0; u < 8; ++u) {
                uint2 mm = smeta[wave][j + u * 2 + half];
                wj[u] = __uint_as_float(mm.y);
                vv[u] = xi8[mm.x * 32 + f];              // 2 edges x 128B / wave
            }
#pragma unroll
            for (int u = 0; u < 8; ++u) {
                int s32 = (int)vv[u];
                a0 = fmaf(wj[u], (float)((s32 << 24) >> 24), a0);
                a1 = fmaf(wj[u], (float)((s32 << 16) >> 24), a1);
                a2 = fmaf(wj[u], (float)((s32 <<  8) >> 24), a2);
                a3 = fmaf(wj[u], (float)( s32        >> 24), a3);
            }
        }
    }
    a0 += __shfl_xor(a0, 32);
    a1 += __shfl_xor(a1, 32);
    a2 += __shfl_xor(a2, 32);
    a3 += __shfl_xor(a3, 32);
    if (half == 0) {
        uint2 o;
        o.x = (f2bf_u(a1) << 16) | f2bf_u(a0);           // features 4f, 4f+1
        o.y = (f2bf_u(a3) << 16) | f2bf_u(a2);           // features 4f+2, 4f+3
        *(uint2*)(aggb + (size_t)node * 64 + f * 2) = o;
    }
}

// ---------- Kernel 3: out = agg_bf16 @ F  (MFMA bf16, single K pass) ----------
#define LDA 136   // 128 + 8 bf16 pad

__global__ __launch_bounds__(256, 2) void k_gemm(
        const unsigned short* __restrict__ A,   // [M][128] bf16 (agg)
        const unsigned short* __restrict__ BT,  // [128][128] bf16, n-major (F^T)
        float* __restrict__ C) {                // [M][128] fp32
    __shared__ unsigned short Abuf[128 * LDA];
    __shared__ unsigned short Bbuf[128 * LDA];
    int t = threadIdx.x;
    int tileM = blockIdx.x * 128;

    for (int i = 0; i < 8; ++i) {
        int c = t + i * 256;
        int r = c >> 4, c8 = c & 15;
        int grow = tileM + r;
        if (grow >= N_NODES) grow = N_NODES - 1;        // clamp; tail rows unused
        uint4 va = *(const uint4*)(A + (long long)grow * 128 + c8 * 8);
        *(uint4*)(Abuf + r * LDA + c8 * 8) = va;
        uint4 vb = *(const uint4*)(BT + r * 128 + c8 * 8);
        *(uint4*)(Bbuf + r * LDA + c8 * 8) = vb;
    }
    __syncthreads();

    int wave = t >> 6, lane = t & 63;
    int wm = (wave >> 1) * 64, wn = (wave & 1) * 64;    // 64x64 per wave
    int m15 = lane & 15, q = lane >> 4;

    f32x4 acc[4][4];
    for (int i = 0; i < 4; ++i)
        for (int j = 0; j < 4; ++j)
            acc[i][j] = f32x4{0.f, 0.f, 0.f, 0.f};

    for (int kk = 0; kk < 128; kk += 32) {
        bf16x8 a[4], b[4];
        for (int i = 0; i < 4; ++i)
            a[i] = *(const bf16x8*)(Abuf + (wm + i * 16 + m15) * LDA + kk + q * 8);
        for (int j = 0; j < 4; ++j)
            b[j] = *(const bf16x8*)(Bbuf + (wn + j * 16 + m15) * LDA + kk + q * 8);
        for (int i = 0; i < 4; ++i)
            for (int j = 0; j < 4; ++j)
                acc[i][j] = __builtin_amdgcn_mfma_f32_16x16x32_bf16(a[i], b[j], acc[i][j], 0, 0, 0);
    }

    // D row = q*4 + reg, col = lane&15 (m89/m91 layout)
    for (int i = 0; i < 4; ++i) {
        int rowbase = tileM + wm + i * 16 + q * 4;
        for (int j = 0; j < 4; ++j) {
            int col = wn + j * 16 + m15;
            for (int r = 0; r < 4; ++r) {
                int grow = rowbase + r;
                if (grow < N_NODES)
                    C[(long long)grow * 128 + col] = acc[i][j][r];
            }
        }
    }
}

extern "C" void kernel_launch(void* const* d_in, const int* in_sizes, int n_in,
                              void* d_out, int out_size, void* d_ws, size_t ws_size,
                              hipStream_t stream) {
    const float* x        = (const float*)d_in[0];
    const float* filters  = (const float*)d_in[1];
    const int*   edge_src = (const int*)d_in[2];
    const int*   edge_dst = (const int*)d_in[3];
    const float* edge_w   = (const float*)d_in[4];
    float* out = (float*)d_out;

    char* ws = (char*)d_ws;
    unsigned short* xi8   = (unsigned short*)(ws);                         // 12.8 MB
    float*          xsc   = (float*)        (ws + 13ll * 1024 * 1024);     // 400 KB
    unsigned int*   aggb  = (unsigned int*) (ws + 14ll * 1024 * 1024);     // 25.6 MB
    unsigned short* fT    = (unsigned short*)(ws + 40ll * 1024 * 1024);    // 32 KB
    int*            rp    = (int*)          (ws + 41ll * 1024 * 1024);     // 400 KB

    hipLaunchKernelGGL(k_prep, dim3(37564), dim3(256), 0, stream,
                       x, xi8, xsc, filters, fT, edge_dst, rp);
    hipLaunchKernelGGL(k_aggregate, dim3(25000), dim3(256), 0, stream,
                       (const unsigned int*)xi8, xsc, edge_src, edge_w, rp, aggb);
    hipLaunchKernelGGL(k_gemm, dim3(782), dim3(256), 0, stream,
                       (const unsigned short*)aggb, fT, out);
}